// Round 7
// baseline (150.669 us; speedup 1.0000x reference)
//
#include <hip/hip_runtime.h>
#include <math.h>

// Problem constants (from reference setup_inputs)
#define NB        4096
#define NH        200
#define HIST_ROWS 100000
#define REG_ROWS  1000
#define NTILES    13        // ceil(200/16) M-tiles, M=208

typedef __attribute__((ext_vector_type(8))) short short8;  // 8 bf16 = 4 VGPRs (MFMA A/B frag)
typedef __attribute__((ext_vector_type(4))) float f32x4;   // MFMA C/D frag

// fp32 -> bf16 round-to-nearest-even (scalar fallback)
__device__ __forceinline__ unsigned short f2bf(float x) {
    union { float f; unsigned u; } v; v.f = x;
    unsigned r = v.u + 0x7FFF + ((v.u >> 16) & 1);
    return (unsigned short)(r >> 16);
}

// packed 2x fp32 -> 2x bf16 in one 32-bit word (v_cvt_pk_bf16_f32 on gfx950)
#if __has_builtin(__builtin_amdgcn_cvt_pk_bf16_f32)
typedef __attribute__((ext_vector_type(2))) __bf16 bf16x2;
__device__ __forceinline__ unsigned pack2bf(float a, float b) {
    union { bf16x2 v; unsigned u; } c;
    c.v = __builtin_amdgcn_cvt_pk_bf16_f32(a, b);
    return c.u;
}
#else
__device__ __forceinline__ unsigned pack2bf(float a, float b) {
    return (unsigned)f2bf(a) | ((unsigned)f2bf(b) << 16);
}
#endif

// Prepass: (a) W_hist|W_reg -> bf16 tables (concat) in ws; (b) block 0 emits
// W1F = W1 in MFMA-fragment order (fp32, 32 KB) for coalesced B' builds.
__global__ __launch_bounds__(256) void prep_tables(
    const float* __restrict__ Wh, const float* __restrict__ Wr,
    const float* __restrict__ W1,
    unsigned short* __restrict__ tab, float* __restrict__ W1F)
{
    const int total4 = (HIST_ROWS + REG_ROWS) * 16;   // float4s
    const int HE4    = HIST_ROWS * 16;
    for (int i = blockIdx.x * blockDim.x + threadIdx.x; i < total4;
         i += gridDim.x * blockDim.x) {
        const float4 v = (i < HE4) ? ((const float4*)Wh)[i]
                                   : ((const float4*)Wr)[i - HE4];
        union { ushort4 s; unsigned u[2]; } o;
        o.u[0] = pack2bf(v.x, v.y);
        o.u[1] = pack2bf(v.z, v.w);
        ((ushort4*)tab)[i] = o.s;
    }
    if (blockIdx.x == 0) {
        for (int i = threadIdx.x; i < 1024; i += 256) {
            const int frag = i >> 6, c = i & 63;
            const int nt = frag >> 2, ks = frag & 3, q = c >> 4, l = c & 15;
            const int k0 = ks * 32 + q * 8, n = nt * 16 + l;
            float tmp[8];
            #pragma unroll
            for (int j = 0; j < 8; ++j) tmp[j] = W1[(k0 + j) * 64 + n];
            float4* dst = (float4*)(W1F + i * 8);
            dst[0] = make_float4(tmp[0], tmp[1], tmp[2], tmp[3]);
            dst[1] = make_float4(tmp[4], tmp[5], tmp[6], tmp[7]);
        }
    }
}

// epilogue for one M-tile: logit = relu(R+b1).W2 (16-lane xor reduce); s from t-col
__device__ __forceinline__ void epi_store(
    const f32x4* accT, const float* w2v, const float* b1v,
    int tl, int quad, int l15, float* logit_lds, float* s_lds)
{
    float part[4] = {0.f, 0.f, 0.f, 0.f};
    #pragma unroll
    for (int nt = 0; nt < 4; ++nt)
        #pragma unroll
        for (int r = 0; r < 4; ++r)
            part[r] += fmaxf(accT[nt][r] + b1v[nt], 0.f) * w2v[nt];
    #pragma unroll
    for (int r = 0; r < 4; ++r) {
        part[r] += __shfl_xor(part[r], 1);
        part[r] += __shfl_xor(part[r], 2);
        part[r] += __shfl_xor(part[r], 4);
        part[r] += __shfl_xor(part[r], 8);
    }
    if (l15 == 0) {
        const int jg = tl * 16 + quad * 4;
        #pragma unroll
        for (int r = 0; r < 4; ++r) {
            logit_lds[jg + r] = part[r];
            s_lds[jg + r]     = accT[4][r];
        }
    }
}

// load one M-tile's 4 A-fragments (row j, this lane)
template <bool BT>
__device__ __forceinline__ void load_A(
    const unsigned short* __restrict__ tab, const unsigned short* __restrict__ tabr,
    const float* __restrict__ W_hist, const float* __restrict__ W_reg,
    const int* hist_lds, const int* hreg_lds, int j, int quad, short8* A)
{
    const int ih = hist_lds[j], ir = hreg_lds[j];
    if (BT) {
        const unsigned short* ph = tab  + (size_t)ih * 64 + quad * 8;
        const unsigned short* pr = tabr + (size_t)ir * 64 + quad * 8;
        A[0] = *(const short8*)(ph);
        A[1] = *(const short8*)(ph + 32);
        A[2] = *(const short8*)(pr);
        A[3] = *(const short8*)(pr + 32);
    } else {
        const float* ph = W_hist + (size_t)ih * 64 + quad * 8;
        const float* pr = W_reg  + (size_t)ir * 64 + quad * 8;
        #pragma unroll
        for (int ks = 0; ks < 4; ++ks) {
            const float* p = (ks < 2 ? ph : pr) + (ks & 1) * 32;
            const float4 v0 = *(const float4*)p, v1 = *(const float4*)(p + 4);
            union { short8 s; unsigned u[4]; } o;
            o.u[0] = pack2bf(v0.x, v0.y); o.u[1] = pack2bf(v0.z, v0.w);
            o.u[2] = pack2bf(v1.x, v1.y); o.u[3] = pack2bf(v1.z, v1.w);
            A[ks] = o.s;
        }
    }
}

// One block per b, 128 threads (2 waves), (128,3): 12 waves/CU as SIX
// independent blocks (vs round 6's three 4-wave blocks) — finer phase
// interleave, barriers stall only 2 waves. ~170 unified regs/wave budget
// (rounds 2/5 proved 4 waves/SIMD spills).
// Algebra: inp@W1 = h@(diag(t)W1), s_j = h_j.t -> B' = [t(x)W1 | t] in LDS
// fragment order (built with packed v_cvt_pk_bf16_f32); A = raw bf16 rows.
// Pipelined pair-of-tiles loop: wave wv does pairs (wv+4it, wv+4it+2);
// next pair's gathers issue after MFMA (A_cur dead), before epilogue.
template <bool BT>
__global__ __launch_bounds__(128, 3) void nais_mfma6(
    const int*   __restrict__ history,
    const int*   __restrict__ target,
    const int*   __restrict__ history_region,
    const int*   __restrict__ target_region,
    const float* __restrict__ W_hist,
    const float* __restrict__ W_tgt,
    const float* __restrict__ W_reg,
    const float* __restrict__ W1,
    const float* __restrict__ b1,
    const float* __restrict__ W2,
    const unsigned short* __restrict__ tab,   // bf16 tables (BT)
    const float* __restrict__ W1F,            // fragment-ordered W1 (BT)
    float*       __restrict__ out)
{
    __shared__ int hist_lds[208];
    __shared__ int hreg_lds[208];
    __shared__ __align__(16) float t_lds[128];
    __shared__ __align__(16) unsigned short Bf[20 * 512];   // 20 frags x 64 chunks x 8 bf16
    __shared__ float logit_lds[208];
    __shared__ float s_lds[208];
    __shared__ float red_e[2], red_p[2];

    const int b   = blockIdx.x;
    const int tid = threadIdx.x;
    const int tgt = target[b];

    // ---- stage indices (rows 200..207 dup row 199) and t ----
    #pragma unroll
    for (int i = tid; i < 208; i += 128) {
        const int jj = i < NH ? i : NH - 1;
        hist_lds[i] = history[b * NH + jj];
        hreg_lds[i] = history_region[b * NH + jj];
    }
    if (tid < 64) {
        t_lds[tid] = W_tgt[(size_t)tgt * 64 + tid];
    } else {
        t_lds[tid] = W_reg[(size_t)target_region[b] * 64 + (tid - 64)];
    }
    __syncthreads();

    const int lane = tid & 63, wv = tid >> 6;   // wv in {0,1}
    const int l15  = lane & 15, quad = lane >> 4;

    // ---- prefetch pair 0 (tiles wv, wv+2): latency hides under B' build ----
    short8 A0[4], A1[4];
    if (BT) {
        const unsigned short* tabr0 = tab + (size_t)HIST_ROWS * 64;
        load_A<true>(tab, tabr0, W_hist, W_reg, hist_lds, hreg_lds,
                     wv * 16 + l15, quad, A0);
        load_A<true>(tab, tabr0, W_hist, W_reg, hist_lds, hreg_lds,
                     (wv + 2) * 16 + l15, quad, A1);
    }

    // ---- build B' fragments: chunks 0..1023 = t(x)W1, 1024..1279 = t col ----
    #pragma unroll
    for (int v = 0; v < 10; ++v) {
        const int i    = tid + v * 128;
        const int frag = i >> 6;
        const int c    = i & 63, q = c >> 4, l = c & 15;
        const int ks   = frag & 3;                // frag<16: frag=nt*4+ks; frag>=16: frag-16
        const int k0   = ks * 32 + q * 8;
        const float4 t0 = *(const float4*)(t_lds + k0);
        const float4 t1 = *(const float4*)(t_lds + k0 + 4);
        union { short8 s; unsigned u[4]; } ob;
        if (frag < 16) {
            float4 w0, w1;
            if (BT) {
                w0 = ((const float4*)W1F)[i * 2];
                w1 = ((const float4*)W1F)[i * 2 + 1];
            } else {
                const int nt = frag >> 2, n = nt * 16 + l;
                float tmp[8];
                #pragma unroll
                for (int j = 0; j < 8; ++j) tmp[j] = W1[(k0 + j) * 64 + n];
                w0 = make_float4(tmp[0], tmp[1], tmp[2], tmp[3]);
                w1 = make_float4(tmp[4], tmp[5], tmp[6], tmp[7]);
            }
            ob.u[0] = pack2bf(w0.x * t0.x, w0.y * t0.y);
            ob.u[1] = pack2bf(w0.z * t0.z, w0.w * t0.w);
            ob.u[2] = pack2bf(w1.x * t1.x, w1.y * t1.y);
            ob.u[3] = pack2bf(w1.z * t1.z, w1.w * t1.w);
        } else {                                   // t column (only l==0 lanes)
            ob.u[0] = (l == 0) ? pack2bf(t0.x, t0.y) : 0u;
            ob.u[1] = (l == 0) ? pack2bf(t0.z, t0.w) : 0u;
            ob.u[2] = (l == 0) ? pack2bf(t1.x, t1.y) : 0u;
            ob.u[3] = (l == 0) ? pack2bf(t1.z, t1.w) : 0u;
        }
        *reinterpret_cast<short8*>(&Bf[i * 8]) = ob.s;
    }
    __syncthreads();   // barrier drain also completes the A0/A1 prefetch

    float w2v[4], b1v[4];
    #pragma unroll
    for (int nt = 0; nt < 4; ++nt) {
        w2v[nt] = W2[nt * 16 + l15];
        b1v[nt] = b1[nt * 16 + l15];
    }

    const unsigned short* tabr = tab + (size_t)HIST_ROWS * 64;

    // ---- pipelined pair loop: pairs (wv+4it, wv+4it+2), it = 0..3 ----
    #pragma unroll 1
    for (int it = 0; it < 4; ++it) {
        const int  tl0 = wv + it * 4;
        const int  tl1 = tl0 + 2;
        if (tl0 >= NTILES) break;
        const bool h1 = (tl1 < NTILES);
        if (!BT) {   // fallback: load current pair directly (no prefetch pipeline)
            const int j0 = tl0 * 16 + l15;
            const int j1 = h1 ? tl1 * 16 + l15 : j0;
            load_A<false>(tab, tabr, W_hist, W_reg, hist_lds, hreg_lds, j0, quad, A0);
            load_A<false>(tab, tabr, W_hist, W_reg, hist_lds, hreg_lds, j1, quad, A1);
        }

        f32x4 acc[2][5];
        #pragma unroll
        for (int tt = 0; tt < 2; ++tt)
            #pragma unroll
            for (int nt = 0; nt < 5; ++nt) acc[tt][nt] = (f32x4){0.f, 0.f, 0.f, 0.f};

        #pragma unroll
        for (int ks = 0; ks < 4; ++ks) {
            short8 bf[5];
            #pragma unroll
            for (int nt = 0; nt < 5; ++nt)
                bf[nt] = *reinterpret_cast<const short8*>(
                    &Bf[((nt * 4 + ks) * 64 + quad * 16 + l15) * 8]);
            #pragma unroll
            for (int nt = 0; nt < 5; ++nt)
                acc[0][nt] = __builtin_amdgcn_mfma_f32_16x16x32_bf16(A0[ks], bf[nt], acc[0][nt], 0, 0, 0);
            if (h1) {
                #pragma unroll
                for (int nt = 0; nt < 5; ++nt)
                    acc[1][nt] = __builtin_amdgcn_mfma_f32_16x16x32_bf16(A1[ks], bf[nt], acc[1][nt], 0, 0, 0);
            }
        }

        // ---- prefetch next pair (A_cur now dead); epilogue hides latency ----
        if (BT && it < 3) {
            const int ntl0 = wv + (it + 1) * 4;
            const int ntl1 = ntl0 + 2;
            if (ntl0 < NTILES) {
                const int nj0 = ntl0 * 16 + l15;
                const int nj1 = (ntl1 < NTILES) ? ntl1 * 16 + l15 : nj0;
                short8 N0[4], N1[4];
                load_A<true>(tab, tabr, W_hist, W_reg, hist_lds, hreg_lds, nj0, quad, N0);
                load_A<true>(tab, tabr, W_hist, W_reg, hist_lds, hreg_lds, nj1, quad, N1);
                epi_store(acc[0], w2v, b1v, tl0, quad, l15, logit_lds, s_lds);
                if (h1) epi_store(acc[1], w2v, b1v, tl1, quad, l15, logit_lds, s_lds);
                #pragma unroll
                for (int ks = 0; ks < 4; ++ks) { A0[ks] = N0[ks]; A1[ks] = N1[ks]; }
                continue;
            }
        }
        epi_store(acc[0], w2v, b1v, tl0, quad, l15, logit_lds, s_lds);
        if (h1) epi_store(acc[1], w2v, b1v, tl1, quad, l15, logit_lds, s_lds);
    }
    __syncthreads();

    // ---- beta-softmax block reduction (rows >= 200 excluded) ----
    float e = 0.f, p = 0.f;
    #pragma unroll
    for (int j = tid; j < NH; j += 128) {
        const float ex = (hist_lds[j] != tgt) ? expf(logit_lds[j]) : 0.f;
        e += ex;
        p += ex * s_lds[j];
    }
    #pragma unroll
    for (int off = 32; off > 0; off >>= 1) {
        e += __shfl_down(e, off);
        p += __shfl_down(p, off);
    }
    if (lane == 0) { red_e[wv] = e; red_p[wv] = p; }
    __syncthreads();
    if (tid == 0) {
        const float E = red_e[0] + red_e[1];
        const float P = red_p[0] + red_p[1];
        const float pred = P / sqrtf(E);      // exp_sum ** 0.5 (BETA = 0.5)
        out[b] = 1.f / (1.f + expf(-pred));
    }
}

extern "C" void kernel_launch(void* const* d_in, const int* in_sizes, int n_in,
                              void* d_out, int out_size, void* d_ws, size_t ws_size,
                              hipStream_t stream) {
    const int*   history        = (const int*)  d_in[0];
    const int*   target         = (const int*)  d_in[1];
    const int*   history_region = (const int*)  d_in[2];
    const int*   target_region  = (const int*)  d_in[3];
    const float* W_hist         = (const float*)d_in[4];
    const float* W_tgt          = (const float*)d_in[5];
    const float* W_reg          = (const float*)d_in[6];
    const float* W1             = (const float*)d_in[7];
    const float* b1             = (const float*)d_in[8];
    const float* W2             = (const float*)d_in[9];
    float* out = (float*)d_out;

    const size_t tab_bytes = (size_t)(HIST_ROWS + REG_ROWS) * 64 * 2;  // 12.93 MB
    const size_t need = tab_bytes + 1024 * 8 * 4;                      // + 32 KB W1F
    if (ws_size >= need) {
        unsigned short* tab = (unsigned short*)d_ws;
        float* W1F = (float*)((char*)d_ws + tab_bytes);
        prep_tables<<<2048, 256, 0, stream>>>(W_hist, W_reg, W1, tab, W1F);
        nais_mfma6<true><<<NB, 128, 0, stream>>>(history, target, history_region, target_region,
                                                 W_hist, W_tgt, W_reg, W1, b1, W2, tab, W1F, out);
    } else {
        nais_mfma6<false><<<NB, 128, 0, stream>>>(history, target, history_region, target_region,
                                                  W_hist, W_tgt, W_reg, W1, b1, W2, nullptr, nullptr, out);
    }
}